// Round 4
// baseline (1857.891 us; speedup 1.0000x reference)
//
#include <hip/hip_runtime.h>
#include <math.h>

// PhaseRefinement fused kernel, v4: R2 traffic structure (x LDS-staged once
// per block, W read once per block from L2) + counted-vmcnt pipeline
// (raw s_barrier, never drain vmcnt to 0 in the main loop).
//
// out = x + LN(c*x)*gamma + beta; LN(c*x) collapses to
//   normed = gamma*(alpha*x - alpha*mu) + beta,
//   alpha = c*rsqrt(c^2*var + 1e-5), mu/var = plain row stats of x.
//
// vmem schedule (exactly 5 vmem ops per body: 4 W-loads + 1 stage):
//   prologue: [W(0) x4][stage 0,1,2]            -> vmcnt(2): stage(0) done
//   body c:   [W(c+1) x4][stage c+3]  compute c -> vmcnt(10): stage(c+1) done
//             (body 0: vmcnt(6); body 15: no barrier)
// Tail bodies clamp W/stage SOURCE indices so op counts stay uniform; the
// stage ring slot (c+3)%4 only ever overwrites buffers whose chunk was
// already consumed.

constexpr int Dh     = 4096;
constexpr int Ph     = 16;
constexpr int NPL    = 32;
constexpr int CHUNK  = 256;          // 64 lanes * 4 floats
constexpr int NCHUNK = Dh / CHUNK;   // 16
constexpr int RPB    = 8;            // rows per block
constexpr int NW     = 8;            // waves per block
constexpr int PPW    = NPL / NW;     // 4 planes per wave
constexpr int BLOCK  = 64 * NW;      // 512
constexpr int DEPTH  = 4;            // x LDS ring depth

__device__ __forceinline__ void stage_chunk(const float* src, float* ldsdst) {
    __builtin_amdgcn_global_load_lds(
        (const __attribute__((address_space(1))) void*)src,
        (__attribute__((address_space(3))) void*)ldsdst, 16, 0, 0);
}

#define WAIT_BAR(N)                                                     \
    do {                                                                \
        asm volatile("s_waitcnt vmcnt(" #N ")" ::: "memory");           \
        __builtin_amdgcn_s_barrier();                                   \
    } while (0)

// One chunk body. C may be runtime (loop) or constant (peeled); WCUR/WNXT are
// named float4[4] arrays (static indices only). TAIL is WAIT_BAR(n) or (void)0.
#define CHUNK_BODY(C, WCUR, WNXT, TAIL)                                       \
    do {                                                                      \
        const int cw_ = ((C) + 1 < NCHUNK) ? (C) + 1 : NCHUNK - 1;            \
        _Pragma("unroll")                                                     \
        for (int p = 0; p < PPW; ++p)                                         \
            WNXT[p] = *(const float4*)(wrow[p] + cw_ * CHUNK);                \
        const int cs_ = ((C) + 3 < NCHUNK) ? (C) + 3 : NCHUNK - 1;            \
        stage_chunk(xsrc + (size_t)cs_ * CHUNK,                               \
                    &x_lds[((C) + 3) & (DEPTH - 1)][wv][0]);                  \
        const float* xb_ = &x_lds[(C) & (DEPTH - 1)][0][0];                   \
        float4 x4_[RPB];                                                      \
        _Pragma("unroll")                                                     \
        for (int r = 0; r < RPB; ++r)                                         \
            x4_[r] = *(const float4*)(xb_ + r * CHUNK + lane * 4);            \
        _Pragma("unroll")                                                     \
        for (int r = 0; r < RPB; ++r) {                                       \
            if (r == wv) {                                                    \
                sx  += x4_[r].x + x4_[r].y + x4_[r].z + x4_[r].w;             \
                sxx += x4_[r].x*x4_[r].x + x4_[r].y*x4_[r].y                  \
                     + x4_[r].z*x4_[r].z + x4_[r].w*x4_[r].w;                 \
            }                                                                 \
            _Pragma("unroll")                                                 \
            for (int p = 0; p < PPW; ++p)                                     \
                acc[r][p] += x4_[r].x*WCUR[p].x + x4_[r].y*WCUR[p].y          \
                           + x4_[r].z*WCUR[p].z + x4_[r].w*WCUR[p].w;         \
        }                                                                     \
        TAIL;                                                                 \
    } while (0)

__global__ __launch_bounds__(BLOCK, 4)
void phase_fused(const float* __restrict__ x,
                 const float* __restrict__ Wr,
                 const float* __restrict__ br,
                 const float* __restrict__ Wo,
                 const float* __restrict__ bo,
                 const float* __restrict__ gamma,
                 const float* __restrict__ beta,
                 float* __restrict__ out)
{
    __shared__ float x_lds[DEPTH][RPB][CHUNK];   // 32 KB ring
    __shared__ float dots_lds[RPB][NPL];
    __shared__ float stats_lds[RPB][2];
    __shared__ float scale_lds[RPB][2];

    const int t    = threadIdx.x;
    const int wv   = t >> 6;
    const int lane = t & 63;
    const size_t rowbase = (size_t)blockIdx.x * RPB;

    // Wave wv's 4 W rows (planes wv*4..+3; 0..15 refine, 16..31 out), lane-folded.
    const float* wrow[PPW];
#pragma unroll
    for (int p = 0; p < PPW; ++p) {
        const int q = wv * PPW + p;
        wrow[p] = ((q < Ph) ? (Wr + (size_t)q * Dh) : (Wo + (size_t)(q - Ph) * Dh))
                  + lane * 4;
    }
    // Wave wv stages row wv; global src is per-lane, LDS dst wave-uniform.
    const float* xsrc = x + (rowbase + wv) * (size_t)Dh + lane * 4;

    float acc[RPB][PPW];
#pragma unroll
    for (int r = 0; r < RPB; ++r)
#pragma unroll
        for (int p = 0; p < PPW; ++p) acc[r][p] = 0.f;
    float sx = 0.f, sxx = 0.f;
    float4 wA[PPW], wB[PPW];

    // Prologue: W(0) then stages 0..2 -> queue [W0 x4, x0, x1, x2].
#pragma unroll
    for (int p = 0; p < PPW; ++p) wA[p] = *(const float4*)(wrow[p]);
    stage_chunk(xsrc,             &x_lds[0][wv][0]);
    stage_chunk(xsrc + CHUNK,     &x_lds[1][wv][0]);
    stage_chunk(xsrc + 2 * CHUNK, &x_lds[2][wv][0]);
    WAIT_BAR(2);   // stage(0) complete (in-order counter), publish buf0

    CHUNK_BODY(0, wA, wB, WAIT_BAR(6));
    CHUNK_BODY(1, wB, wA, WAIT_BAR(10));
    for (int cc = 2; cc < NCHUNK - 2; cc += 2) {
        CHUNK_BODY(cc,     wA, wB, WAIT_BAR(10));
        CHUNK_BODY(cc + 1, wB, wA, WAIT_BAR(10));
    }
    CHUNK_BODY(NCHUNK - 2, wA, wB, WAIT_BAR(10));
    CHUNK_BODY(NCHUNK - 1, wB, wA, (void)0);

    // Butterfly-reduce accumulators across the 64 lanes.
#pragma unroll
    for (int r = 0; r < RPB; ++r)
#pragma unroll
        for (int p = 0; p < PPW; ++p) {
            float v = acc[r][p];
#pragma unroll
            for (int m = 1; m < 64; m <<= 1) v += __shfl_xor(v, m, 64);
            if (lane == 0) dots_lds[r][wv * PPW + p] = v;
        }
#pragma unroll
    for (int m = 1; m < 64; m <<= 1) {
        sx  += __shfl_xor(sx, m, 64);
        sxx += __shfl_xor(sxx, m, 64);
    }
    if (lane == 0) { stats_lds[wv][0] = sx; stats_lds[wv][1] = sxx; }
    __syncthreads();

    // Scalar phase, parallel over (row, plane): 128 threads, 16-lane reduce.
    if (t < RPB * Ph) {
        const int r = t >> 4, p = t & 15;
        float d1 = dots_lds[r][p]      + br[p];
        float d2 = dots_lds[r][Ph + p] + bo[p];
        float cd = cosf((tanhf(d1) - tanhf(d2)) * 3.14159265358979323846f);
#pragma unroll
        for (int m = 1; m < 16; m <<= 1) cd += __shfl_xor(cd, m, 16);
        if (p == 0) {
            float s    = cd;
            float gain = log1pf(expf(s * (1.f / Ph) + 0.5f));  // softplus
            float cm   = s * gain * (1.f / Ph);
            float mu   = stats_lds[r][0] * (1.f / Dh);
            float var  = stats_lds[r][1] * (1.f / Dh) - mu * mu;
            var = fmaxf(var, 0.f);
            float rstd  = rsqrtf(cm * cm * var + 1e-5f);
            float alpha = cm * rstd;
            scale_lds[r][0] = alpha;
            scale_lds[r][1] = alpha * mu;
        }
    }
    __syncthreads();

    // Phase B, column-sliced: wave wv owns cols [wv*512, wv*512+512);
    // gamma/beta loaded ONCE per wave and reused across all 8 rows.
    {
        const int col0 = wv * 512 + lane * 4;
        const float4 g4a = *(const float4*)(gamma + col0);
        const float4 g4b = *(const float4*)(gamma + col0 + 256);
        const float4 b4a = *(const float4*)(beta  + col0);
        const float4 b4b = *(const float4*)(beta  + col0 + 256);
#pragma unroll
        for (int r = 0; r < RPB; ++r) {
            const float alpha = scale_lds[r][0];
            const float am    = scale_lds[r][1];
            const float* xr  = x   + (rowbase + r) * (size_t)Dh;
            float*       orw = out + (rowbase + r) * (size_t)Dh;
            float4 xa = *(const float4*)(xr + col0);
            float4 xb = *(const float4*)(xr + col0 + 256);
            float4 oa, ob;
            oa.x = xa.x + g4a.x * (alpha * xa.x - am) + b4a.x;
            oa.y = xa.y + g4a.y * (alpha * xa.y - am) + b4a.y;
            oa.z = xa.z + g4a.z * (alpha * xa.z - am) + b4a.z;
            oa.w = xa.w + g4a.w * (alpha * xa.w - am) + b4a.w;
            ob.x = xb.x + g4b.x * (alpha * xb.x - am) + b4b.x;
            ob.y = xb.y + g4b.y * (alpha * xb.y - am) + b4b.y;
            ob.z = xb.z + g4b.z * (alpha * xb.z - am) + b4b.z;
            ob.w = xb.w + g4b.w * (alpha * xb.w - am) + b4b.w;
            *(float4*)(orw + col0)       = oa;
            *(float4*)(orw + col0 + 256) = ob;
        }
    }
}

extern "C" void kernel_launch(void* const* d_in, const int* in_sizes, int n_in,
                              void* d_out, int out_size, void* d_ws, size_t ws_size,
                              hipStream_t stream)
{
    const float* x     = (const float*)d_in[0];
    const float* Wr    = (const float*)d_in[1];
    const float* br    = (const float*)d_in[2];
    const float* Wo    = (const float*)d_in[3];
    const float* bo    = (const float*)d_in[4];
    const float* gamma = (const float*)d_in[5];
    const float* beta  = (const float*)d_in[6];
    float* out = (float*)d_out;

    const int B = in_sizes[0] / Dh;       // 32768
    dim3 grid(B / RPB);                   // 4096 blocks
    phase_fused<<<grid, BLOCK, 0, stream>>>(x, Wr, br, Wo, bo, gamma, beta, out);
}

// Round 5
// 388.350 us; speedup vs baseline: 4.7841x; 4.7841x over previous
//
#include <hip/hip_runtime.h>
#include <math.h>

// PhaseRefinement fused kernel, v5: R3's barrier-free main loop with the
// register handbrake released. R2/R3/R4 all compiled to exactly 64 VGPR
// (__launch_bounds__(512,4) clamped the allocator) -> the 12 independent
// loads per chunk were SERIALIZED (no registers to batch them), making every
// chunk cost ~8-12 sequential memory latencies. R4's peeled bodies spilled
// outright (FETCH 2.8GB / WRITE 4.4GB of scratch). Fix: __launch_bounds__
// (512,2) -> ~128 VGPR budget, 12 loads batched in flight, ~4 waves/SIMD.
//
// out = x + LN(c*x)*gamma + beta; LN(c*x) collapses to
//   normed = gamma*(alpha*x - alpha*mu) + beta,
//   alpha = c*rsqrt(c^2*var + 1e-5), mu/var = plain row stats of x.

constexpr int Dh     = 4096;
constexpr int Ph     = 16;
constexpr int NPL    = 32;          // 2*P dots per row
constexpr int CHUNK  = 256;         // 64 lanes * 4 floats
constexpr int NCHUNK = Dh / CHUNK;  // 16
constexpr int RPB    = 8;           // rows per block
constexpr int NW     = 8;           // waves per block
constexpr int PPW    = NPL / NW;    // 4 planes per wave
constexpr int BLOCK  = 64 * NW;     // 512

__global__ __launch_bounds__(BLOCK, 2)
void phase_fused(const float* __restrict__ x,
                 const float* __restrict__ Wr,
                 const float* __restrict__ br,
                 const float* __restrict__ Wo,
                 const float* __restrict__ bo,
                 const float* __restrict__ gamma,
                 const float* __restrict__ beta,
                 float* __restrict__ out)
{
    __shared__ float dots_lds[RPB][NPL];
    __shared__ float stats_lds[RPB][2];
    __shared__ float scale_lds[RPB][2];

    const int t    = threadIdx.x;
    const int wv   = t >> 6;
    const int lane = t & 63;
    const size_t rowbase = (size_t)blockIdx.x * RPB;

    // Per-lane base pointers (lane offset folded in).
    const float* xrow[RPB];
#pragma unroll
    for (int r = 0; r < RPB; ++r)
        xrow[r] = x + (rowbase + r) * (size_t)Dh + lane * 4;

    const float* wrow[PPW];
#pragma unroll
    for (int p = 0; p < PPW; ++p) {
        const int q = wv * PPW + p;
        wrow[p] = ((q < Ph) ? (Wr + (size_t)q * Dh) : (Wo + (size_t)(q - Ph) * Dh))
                  + lane * 4;
    }

    float acc[RPB][PPW];
#pragma unroll
    for (int r = 0; r < RPB; ++r)
#pragma unroll
        for (int p = 0; p < PPW; ++p) acc[r][p] = 0.f;
    float sx = 0.f, sxx = 0.f;

    for (int c = 0; c < NCHUNK; ++c) {
        const int off = c * CHUNK;
        // 12 independent loads, batched (now we have the VGPRs for it).
        float4 x4[RPB];
#pragma unroll
        for (int r = 0; r < RPB; ++r)
            x4[r] = *(const float4*)(xrow[r] + off);
        float4 w4[PPW];
#pragma unroll
        for (int p = 0; p < PPW; ++p)
            w4[p] = *(const float4*)(wrow[p] + off);

#pragma unroll
        for (int r = 0; r < RPB; ++r) {
            if (r == wv) {  // wave-uniform scalar branch; static indices
                sx  += x4[r].x + x4[r].y + x4[r].z + x4[r].w;
                sxx += x4[r].x*x4[r].x + x4[r].y*x4[r].y
                     + x4[r].z*x4[r].z + x4[r].w*x4[r].w;
            }
#pragma unroll
            for (int p = 0; p < PPW; ++p)
                acc[r][p] += x4[r].x*w4[p].x + x4[r].y*w4[p].y
                           + x4[r].z*w4[p].z + x4[r].w*w4[p].w;
        }
    }

    // Butterfly-reduce accumulators across the 64 lanes.
#pragma unroll
    for (int r = 0; r < RPB; ++r)
#pragma unroll
        for (int p = 0; p < PPW; ++p) {
            float v = acc[r][p];
#pragma unroll
            for (int m = 1; m < 64; m <<= 1) v += __shfl_xor(v, m, 64);
            if (lane == 0) dots_lds[r][wv * PPW + p] = v;
        }
#pragma unroll
    for (int m = 1; m < 64; m <<= 1) {
        sx  += __shfl_xor(sx, m, 64);
        sxx += __shfl_xor(sxx, m, 64);
    }
    if (lane == 0) { stats_lds[wv][0] = sx; stats_lds[wv][1] = sxx; }
    __syncthreads();

    // Scalar phase, parallel over (row, plane): 128 threads, 16-lane reduce.
    if (t < RPB * Ph) {
        const int r = t >> 4, p = t & 15;
        float d1 = dots_lds[r][p]      + br[p];
        float d2 = dots_lds[r][Ph + p] + bo[p];
        float cd = cosf((tanhf(d1) - tanhf(d2)) * 3.14159265358979323846f);
#pragma unroll
        for (int m = 1; m < 16; m <<= 1) cd += __shfl_xor(cd, m, 16);
        if (p == 0) {
            float s    = cd;
            float gain = log1pf(expf(s * (1.f / Ph) + 0.5f));  // softplus
            float cm   = s * gain * (1.f / Ph);
            float mu   = stats_lds[r][0] * (1.f / Dh);
            float var  = stats_lds[r][1] * (1.f / Dh) - mu * mu;
            var = fmaxf(var, 0.f);
            float rstd  = rsqrtf(cm * cm * var + 1e-5f);
            float alpha = cm * rstd;
            scale_lds[r][0] = alpha;
            scale_lds[r][1] = alpha * mu;
        }
    }
    __syncthreads();

    // Phase B, column-sliced: wave wv owns cols [wv*512, wv*512+512);
    // gamma/beta loaded ONCE per wave, reused across all 8 rows. x re-read
    // is L1/L2-hot (FETCH_SIZE has confirmed x-once at HBM every round).
    {
        const int col0 = wv * 512 + lane * 4;
        const float4 g4a = *(const float4*)(gamma + col0);
        const float4 g4b = *(const float4*)(gamma + col0 + 256);
        const float4 b4a = *(const float4*)(beta  + col0);
        const float4 b4b = *(const float4*)(beta  + col0 + 256);
#pragma unroll
        for (int r = 0; r < RPB; ++r) {
            const float alpha = scale_lds[r][0];
            const float am    = scale_lds[r][1];
            const float* xr  = x   + (rowbase + r) * (size_t)Dh;
            float*       orw = out + (rowbase + r) * (size_t)Dh;
            float4 xa = *(const float4*)(xr + col0);
            float4 xb = *(const float4*)(xr + col0 + 256);
            float4 oa, ob;
            oa.x = xa.x + g4a.x * (alpha * xa.x - am) + b4a.x;
            oa.y = xa.y + g4a.y * (alpha * xa.y - am) + b4a.y;
            oa.z = xa.z + g4a.z * (alpha * xa.z - am) + b4a.z;
            oa.w = xa.w + g4a.w * (alpha * xa.w - am) + b4a.w;
            ob.x = xb.x + g4b.x * (alpha * xb.x - am) + b4b.x;
            ob.y = xb.y + g4b.y * (alpha * xb.y - am) + b4b.y;
            ob.z = xb.z + g4b.z * (alpha * xb.z - am) + b4b.z;
            ob.w = xb.w + g4b.w * (alpha * xb.w - am) + b4b.w;
            *(float4*)(orw + col0)       = oa;
            *(float4*)(orw + col0 + 256) = ob;
        }
    }
}

extern "C" void kernel_launch(void* const* d_in, const int* in_sizes, int n_in,
                              void* d_out, int out_size, void* d_ws, size_t ws_size,
                              hipStream_t stream)
{
    const float* x     = (const float*)d_in[0];
    const float* Wr    = (const float*)d_in[1];
    const float* br    = (const float*)d_in[2];
    const float* Wo    = (const float*)d_in[3];
    const float* bo    = (const float*)d_in[4];
    const float* gamma = (const float*)d_in[5];
    const float* beta  = (const float*)d_in[6];
    float* out = (float*)d_out;

    const int B = in_sizes[0] / Dh;       // 32768
    dim3 grid(B / RPB);                   // 4096 blocks
    phase_fused<<<grid, BLOCK, 0, stream>>>(x, Wr, br, Wo, bo, gamma, beta, out);
}